// Round 4
// baseline (1293.772 us; speedup 1.0000x reference)
//
#include <hip/hip_runtime.h>
#include <hip/hip_bf16.h>
#include <hip/hip_fp16.h>
#include <math.h>

#define NPROJ 1024
#define NHEADS 4
#define NHID 256
#define NGRAPH 64

typedef _Float16 half8 __attribute__((ext_vector_type(8)));
typedef _Float16 half4v __attribute__((ext_vector_type(4)));
typedef float floatx4 __attribute__((ext_vector_type(4)));

// ============================================================
// Split-precision f16 MFMA GEMM, NO-LDS variant:
//   C = Ah@BhT^T + Ah@BlT^T + Al@BhT^T   (K fixed = 1024)
// A: M x 1024 row-major (hi/lo f16).  B TRANSPOSED: Nc x 1024 (hi/lo).
// MFMA fragments are 16B-contiguous in K for both operands, so each lane
// loads its fragment straight from global (L1/L2 serve the 2x wave reuse).
// No LDS, no barriers. 128x128 tile, 4 waves (2x2), wave 64x64.
// XCD-chunked grid: each XCD owns mpad8 contiguous row-slabs, bx fastest.
// ============================================================
template<int ACT, int OUT>  // ACT: 0 none, 1 tanh; OUT: 0 f32, 1 split pair, 2 f16
__global__ __launch_bounds__(256) void gemm_mfma(
    const _Float16* __restrict__ Ah, const _Float16* __restrict__ Al,
    const _Float16* __restrict__ BhT, const _Float16* __restrict__ BlT,
    const float* __restrict__ bias, float* __restrict__ Cf,
    _Float16* __restrict__ Ch, _Float16* __restrict__ Cl,
    int M, int Nc, int lgn, int mpad8)
{
  const int id  = blockIdx.x;
  const int xcd = id & 7;
  const int kk  = id >> 3;
  const int bx  = kk & ((1 << lgn) - 1);
  const int by  = xcd * mpad8 + (kk >> lgn);
  const int m0  = by * 128, n0 = bx * 128;
  if (m0 >= M) return;

  const int tid  = threadIdx.x;
  const int lane = tid & 63;
  const int wave = tid >> 6;
  const int wm = wave >> 1, wn = wave & 1;
  const int l15 = lane & 15;
  const int kq  = (lane >> 4) * 8;   // fragment k-offset (elems)

  // per-lane fragment base pointers
  const _Float16* pa[4];
  const _Float16* qa[4];
  const _Float16* pb[4];
  const _Float16* qb[4];
#pragma unroll
  for (int i = 0; i < 4; ++i) {
    int r = m0 + wm * 64 + i * 16 + l15;
    r = r < M ? r : (M - 1);
    pa[i] = Ah + (size_t)r * 1024 + kq;
    qa[i] = Al + (size_t)r * 1024 + kq;
  }
#pragma unroll
  for (int j = 0; j < 4; ++j) {
    const int c = n0 + wn * 64 + j * 16 + l15;
    pb[j] = BhT + (size_t)c * 1024 + kq;
    qb[j] = BlT + (size_t)c * 1024 + kq;
  }

  floatx4 acc[4][4] = {};

#pragma unroll 2
  for (int k = 0; k < 32; ++k) {
    const int ko = k * 32;
    half8 ah[4], al[4], bh[4], bl[4];
#pragma unroll
    for (int i = 0; i < 4; ++i) ah[i] = *(const half8*)(pa[i] + ko);
#pragma unroll
    for (int j = 0; j < 4; ++j) bh[j] = *(const half8*)(pb[j] + ko);
#pragma unroll
    for (int i = 0; i < 4; ++i) al[i] = *(const half8*)(qa[i] + ko);
#pragma unroll
    for (int j = 0; j < 4; ++j) bl[j] = *(const half8*)(qb[j] + ko);

#pragma unroll
    for (int i = 0; i < 4; ++i)
#pragma unroll
      for (int j = 0; j < 4; ++j)
        acc[i][j] = __builtin_amdgcn_mfma_f32_16x16x32_f16(ah[i], bh[j],
                                                           acc[i][j], 0, 0, 0);
#pragma unroll
    for (int i = 0; i < 4; ++i)
#pragma unroll
      for (int j = 0; j < 4; ++j)
        acc[i][j] = __builtin_amdgcn_mfma_f32_16x16x32_f16(ah[i], bl[j],
                                                           acc[i][j], 0, 0, 0);
#pragma unroll
    for (int i = 0; i < 4; ++i)
#pragma unroll
      for (int j = 0; j < 4; ++j)
        acc[i][j] = __builtin_amdgcn_mfma_f32_16x16x32_f16(al[i], bh[j],
                                                           acc[i][j], 0, 0, 0);
  }

  // epilogue: C[row = (lane>>4)*4 + reg, col = lane&15] per 16x16 frag
  const int rbase = (lane >> 4) * 4;
#pragma unroll
  for (int j = 0; j < 4; ++j) {
    const int col = n0 + wn * 64 + j * 16 + l15;
    const float bv = bias ? bias[col] : 0.f;
#pragma unroll
    for (int i = 0; i < 4; ++i) {
      const int gm0 = m0 + wm * 64 + i * 16 + rbase;
#pragma unroll
      for (int r = 0; r < 4; ++r) {
        const int gm = gm0 + r;
        if (gm >= M) continue;
        float v = acc[i][j][r] + bv;
        if (ACT == 1) v = tanhf(v);
        if (OUT == 1) {
          _Float16 hh = (_Float16)v;
          Ch[(size_t)gm * Nc + col] = hh;
          Cl[(size_t)gm * Nc + col] = (_Float16)(v - (float)hh);
        } else if (OUT == 2) {
          Ch[(size_t)gm * Nc + col] = (_Float16)v;
        } else {
          Cf[(size_t)gm * Nc + col] = v;
        }
      }
    }
  }
}

// ============================================================
// splitters
// ============================================================
__global__ void k_split8(const float* __restrict__ in, _Float16* __restrict__ h,
                         _Float16* __restrict__ l, int L8) {
  int i = blockIdx.x * 256 + threadIdx.x;
  if (i >= L8) return;
  const float4* p = (const float4*)(in + (size_t)i * 8);
  float4 v0 = p[0], v1 = p[1];
  float vv[8] = {v0.x, v0.y, v0.z, v0.w, v1.x, v1.y, v1.z, v1.w};
  half8 hv, lv;
#pragma unroll
  for (int j = 0; j < 8; ++j) {
    _Float16 hh = (_Float16)vv[j];
    hv[j] = hh;
    lv[j] = (_Float16)(vv[j] - (float)hh);
  }
  *(half8*)(h + (size_t)i * 8) = hv;
  *(half8*)(l + (size_t)i * 8) = lv;
}

// W (K x Nc) fp32 -> transposed split (Nc x K) f16 hi/lo
__global__ __launch_bounds__(256) void k_splitT(const float* __restrict__ in,
                                                _Float16* __restrict__ hT,
                                                _Float16* __restrict__ lT,
                                                int K, int Nc) {
  __shared__ float t[32][33];
  const int tx = threadIdx.x & 31, ty = threadIdx.x >> 5;
  const int c0 = blockIdx.x * 32, k0 = blockIdx.y * 32;
#pragma unroll
  for (int r = 0; r < 4; ++r)
    t[ty + 8 * r][tx] = in[(size_t)(k0 + ty + 8 * r) * Nc + c0 + tx];
  __syncthreads();
#pragma unroll
  for (int r = 0; r < 4; ++r) {
    float v = t[tx][ty + 8 * r];
    int oc = c0 + ty + 8 * r;
    _Float16 hh = (_Float16)v;
    hT[(size_t)oc * K + k0 + tx] = hh;
    lT[(size_t)oc * K + k0 + tx] = (_Float16)(v - (float)hh);
  }
}

// ============================================================
// CSR-by-dst construction (recomputed every call; no caching)
// ============================================================
__global__ void k_init_counts(int* cnt, int n) {
  int i = blockIdx.x * 256 + threadIdx.x;
  if (i < n) cnt[i] = 1;  // self-loop pre-counted
}

__global__ void k_count(const int* __restrict__ dst, int* cnt, int e) {
  int i = blockIdx.x * 256 + threadIdx.x;
  if (i < e) atomicAdd(&cnt[dst[i]], 1);
}

__global__ __launch_bounds__(1024) void k_scan(const int* __restrict__ cnt,
                                               int* __restrict__ rowstart,
                                               int* __restrict__ cursor, int n) {
  __shared__ int buf[1024];
  __shared__ int carry;
  int t = threadIdx.x;
  if (t == 0) carry = 0;
  __syncthreads();
  for (int base = 0; base < n; base += 1024) {
    int x = (base + t < n) ? cnt[base + t] : 0;
    buf[t] = x;
    __syncthreads();
    for (int off = 1; off < 1024; off <<= 1) {
      int v = (t >= off) ? buf[t - off] : 0;
      __syncthreads();
      buf[t] += v;
      __syncthreads();
    }
    int c0 = carry;
    int excl = buf[t] - x + c0;
    if (base + t < n) { rowstart[base + t] = excl; cursor[base + t] = excl; }
    __syncthreads();
    if (t == 0) carry = c0 + buf[1023];
    __syncthreads();
  }
  if (t == 0) rowstart[n] = carry;
}

__global__ void k_fill(const int* __restrict__ src, const int* __restrict__ dst,
                       int* cursor, int* __restrict__ col, int e) {
  int i = blockIdx.x * 256 + threadIdx.x;
  if (i < e) {
    int p = atomicAdd(&cursor[dst[i]], 1);
    col[p] = src[i];
  }
}

__global__ void k_fill_self(int* cursor, int* __restrict__ col, int n) {
  int i = blockIdx.x * 256 + threadIdx.x;
  if (i < n) {
    int p = atomicAdd(&cursor[i], 1);
    col[p] = i;
  }
}

// ============================================================
// per-node attention logits (f16 h): one wave per head
// ============================================================
__global__ __launch_bounds__(256) void k_alpha(
    const _Float16* __restrict__ h, const float* __restrict__ a_src,
    const float* __restrict__ a_dst, float* __restrict__ as_out,
    float* __restrict__ ad_out) {
  int n = blockIdx.x, t = threadIdx.x;
  const int wv = t >> 6, ln = t & 63;     // wave = head
  const int cb = wv * 256 + 4 * ln;
  half4v v = *(const half4v*)(h + (size_t)n * NPROJ + cb);
  float4 s4 = *(const float4*)(a_src + cb);
  float4 d4 = *(const float4*)(a_dst + cb);
  float vv[4] = {(float)v[0], (float)v[1], (float)v[2], (float)v[3]};
  float ss = vv[0] * s4.x + vv[1] * s4.y + vv[2] * s4.z + vv[3] * s4.w;
  float sd = vv[0] * d4.x + vv[1] * d4.y + vv[2] * d4.z + vv[3] * d4.w;
#pragma unroll
  for (int off = 32; off > 0; off >>= 1) {
    ss += __shfl_down(ss, off);
    sd += __shfl_down(sd, off);
  }
  if (ln == 0) {
    as_out[n * 4 + wv] = ss;
    ad_out[n * 4 + wv] = sd;
  }
}

// ============================================================
// fused segment-softmax + aggregation (f16 h, 2 edges/iter)
//        + bias + ELU + residual + LayerNorm
// one workgroup (256 threads) per destination node;
// gather phase: group g = t>>7 handles edges e%2==g, 16B half8 loads
// ============================================================
__device__ __forceinline__ float lrelu02(float x) {
  return x > 0.f ? x : 0.2f * x;
}

__global__ __launch_bounds__(256) void k_aggregate_ln(
    const _Float16* __restrict__ h, const float* __restrict__ as_,
    const float* __restrict__ ad_, const int* __restrict__ rowstart,
    const int* __restrict__ col, const float* __restrict__ bias,
    const float* __restrict__ gamma, const float* __restrict__ beta,
    _Float16* __restrict__ xh, _Float16* __restrict__ xl) {
  __shared__ float redm[4][256];
  __shared__ float wts[256][4];
  __shared__ int scol[256];
  __shared__ float combo[128][8];
  __shared__ float Mh[4], Sh[4];
  __shared__ float mu_s, rstd_s;

  int n = blockIdx.x, t = threadIdx.x;
  int rs = rowstart[n], re = rowstart[n + 1];
  float4 ad4 = *(const float4*)(ad_ + n * 4);
  float adn[4] = {ad4.x, ad4.y, ad4.z, ad4.w};

  // pass 1: per-head max
  float mx[4] = {-1e30f, -1e30f, -1e30f, -1e30f};
  for (int e = rs + t; e < re; e += 256) {
    int s = col[e];
    float4 a4 = *(const float4*)(as_ + (size_t)s * 4);
    float av[4] = {a4.x, a4.y, a4.z, a4.w};
#pragma unroll
    for (int j = 0; j < 4; ++j)
      mx[j] = fmaxf(mx[j], lrelu02(av[j] + adn[j]));
  }
#pragma unroll
  for (int j = 0; j < 4; ++j) redm[j][t] = mx[j];
  __syncthreads();
  for (int s = 128; s > 0; s >>= 1) {
    if (t < s)
#pragma unroll
      for (int j = 0; j < 4; ++j)
        redm[j][t] = fmaxf(redm[j][t], redm[j][t + s]);
    __syncthreads();
  }
  if (t < 4) Mh[t] = redm[t][0];
  __syncthreads();
  float M_[4];
#pragma unroll
  for (int j = 0; j < 4; ++j) M_[j] = Mh[j];
  __syncthreads();

  // pass 2: sum of exp
  float sm[4] = {0.f, 0.f, 0.f, 0.f};
  for (int e = rs + t; e < re; e += 256) {
    int s = col[e];
    float4 a4 = *(const float4*)(as_ + (size_t)s * 4);
    float av[4] = {a4.x, a4.y, a4.z, a4.w};
#pragma unroll
    for (int j = 0; j < 4; ++j)
      sm[j] += expf(lrelu02(av[j] + adn[j]) - M_[j]);
  }
#pragma unroll
  for (int j = 0; j < 4; ++j) redm[j][t] = sm[j];
  __syncthreads();
  for (int s = 128; s > 0; s >>= 1) {
    if (t < s)
#pragma unroll
      for (int j = 0; j < 4; ++j) redm[j][t] += redm[j][t + s];
    __syncthreads();
  }
  if (t < 4) Sh[t] = redm[t][0];
  __syncthreads();
  float S_[4];
#pragma unroll
  for (int j = 0; j < 4; ++j) S_[j] = Sh[j] + 1e-16f;
  __syncthreads();

  // pass 3: weighted aggregation; group g over edges, 8 f16 cols per thread
  const int g = t >> 7, c = t & 127;
  const int hd = c >> 5;
  float acc8[8] = {};
  for (int c0 = rs; c0 < re; c0 += 256) {
    int cnt = min(256, re - c0);
    if (t < cnt) {
      int s = col[c0 + t];
      scol[t] = s;
      float4 a4 = *(const float4*)(as_ + (size_t)s * 4);
      float av[4] = {a4.x, a4.y, a4.z, a4.w};
#pragma unroll
      for (int j = 0; j < 4; ++j)
        wts[t][j] = expf(lrelu02(av[j] + adn[j]) - M_[j]) / S_[j];
    }
    __syncthreads();
    for (int e = g; e < cnt; e += 2) {
      float w = wts[e][hd];
      half8 hv = *(const half8*)(h + (size_t)scol[e] * NPROJ + 8 * c);
#pragma unroll
      for (int j = 0; j < 8; ++j) acc8[j] = fmaf(w, (float)hv[j], acc8[j]);
    }
    __syncthreads();
  }
  // combine the two edge-groups
  if (g == 1) {
#pragma unroll
    for (int j = 0; j < 8; ++j) combo[c][j] = acc8[j];
  }
  __syncthreads();
  if (g == 0) {
#pragma unroll
    for (int j = 0; j < 8; ++j) acc8[j] += combo[c][j];
  }

  // epilogue: bias, ELU, residual, LayerNorm (t<128 own cols 8c..8c+7)
  const size_t base = (size_t)n * NPROJ + 8 * c;
  float v[8];
  float sum = 0.f, sumsq = 0.f;
  if (g == 0) {
    float4 b0 = *(const float4*)(bias + 8 * c);
    float4 b1 = *(const float4*)(bias + 8 * c + 4);
    float bvv[8] = {b0.x, b0.y, b0.z, b0.w, b1.x, b1.y, b1.z, b1.w};
    half8 xhv = *(const half8*)(xh + base);
    half8 xlv = *(const half8*)(xl + base);
#pragma unroll
    for (int j = 0; j < 8; ++j) {
      float u = acc8[j] + bvv[j];
      u = u > 0.f ? u : expm1f(u);
      u += (float)xhv[j] + (float)xlv[j];
      v[j] = u;
      sum += u;
      sumsq += u * u;
    }
  }
  redm[0][t] = g == 0 ? sum : 0.f;
  redm[1][t] = g == 0 ? sumsq : 0.f;
  __syncthreads();
  for (int s = 64; s > 0; s >>= 1) {
    if (t < s) {
      redm[0][t] += redm[0][t + s];
      redm[1][t] += redm[1][t + s];
    }
    __syncthreads();
  }
  if (t == 0) {
    float mu = redm[0][0] * (1.f / 1024.f);
    float var = redm[1][0] * (1.f / 1024.f) - mu * mu;
    mu_s = mu;
    rstd_s = rsqrtf(var + 1e-5f);
  }
  __syncthreads();
  if (g == 0) {
    float mu = mu_s, rstd = rstd_s;
    float4 g0 = *(const float4*)(gamma + 8 * c);
    float4 g1 = *(const float4*)(gamma + 8 * c + 4);
    float4 e0 = *(const float4*)(beta + 8 * c);
    float4 e1 = *(const float4*)(beta + 8 * c + 4);
    float gvv[8] = {g0.x, g0.y, g0.z, g0.w, g1.x, g1.y, g1.z, g1.w};
    float bev[8] = {e0.x, e0.y, e0.z, e0.w, e1.x, e1.y, e1.z, e1.w};
    half8 oh, ol;
#pragma unroll
    for (int j = 0; j < 8; ++j) {
      float y = (v[j] - mu) * rstd * gvv[j] + bev[j];
      _Float16 hh = (_Float16)y;
      oh[j] = hh;
      ol[j] = (_Float16)(y - (float)hh);
    }
    *(half8*)(xh + base) = oh;
    *(half8*)(xl + base) = ol;
  }
}

// ============================================================
// pooling + classifier
// ============================================================
__global__ void k_scores(const float* __restrict__ tb,
                         const float* __restrict__ W2,
                         const float* __restrict__ b2,
                         float* __restrict__ scores, int N) {
  int n = blockIdx.x, lane = threadIdx.x;
  float s = 0.f;
  for (int k = lane; k < 512; k += 64) s = fmaf(tb[(size_t)n * 512 + k], W2[k], s);
  for (int off = 32; off > 0; off >>= 1) s += __shfl_down(s, off);
  if (lane == 0) scores[n] = s + b2[0];
}

__global__ void k_grange_init(int* gstart, int* gend, int N) {
  int g = threadIdx.x;
  if (g < NGRAPH) { gstart[g] = N; gend[g] = 0; }
}

__global__ void k_grange_mark(const int* __restrict__ batch, int* gstart,
                              int* gend, int N) {
  int n = blockIdx.x * 256 + threadIdx.x;
  if (n >= N) return;
  int b = batch[n];
  if (n == 0 || batch[n - 1] != b) gstart[b] = n;
  if (n == N - 1 || batch[n + 1] != b) gend[b] = n + 1;
}

__global__ __launch_bounds__(256) void k_pool(
    const float* __restrict__ scores, const _Float16* __restrict__ xh,
    const _Float16* __restrict__ xl, const int* __restrict__ gstart,
    const int* __restrict__ gend, float* __restrict__ pooled) {
  __shared__ float red[256];
  __shared__ float wt[256];
  __shared__ float m_s, s_s;
  int g = blockIdx.x, t = threadIdx.x;
  int rs = gstart[g], re = gend[g];

  float mx = -1e30f;
  for (int i = rs + t; i < re; i += 256) mx = fmaxf(mx, scores[i]);
  red[t] = mx;
  __syncthreads();
  for (int s = 128; s > 0; s >>= 1) {
    if (t < s) red[t] = fmaxf(red[t], red[t + s]);
    __syncthreads();
  }
  if (t == 0) m_s = red[0];
  __syncthreads();
  float m = m_s;

  float sm = 0.f;
  for (int i = rs + t; i < re; i += 256) sm += expf(scores[i] - m);
  red[t] = sm;
  __syncthreads();
  for (int s = 128; s > 0; s >>= 1) {
    if (t < s) red[t] += red[t + s];
    __syncthreads();
  }
  if (t == 0) s_s = red[0] + 1e-16f;
  __syncthreads();
  float sden = s_s;

  float acc[4] = {0.f, 0.f, 0.f, 0.f};
  for (int c0 = rs; c0 < re; c0 += 256) {
    int cnt = min(256, re - c0);
    if (t < cnt) wt[t] = expf(scores[c0 + t] - m) / sden;
    __syncthreads();
    for (int e = 0; e < cnt; ++e) {
      float w = wt[e];
      size_t base = (size_t)(c0 + e) * NPROJ + 4 * t;
      half4v hv = *(const half4v*)(xh + base);
      half4v lv = *(const half4v*)(xl + base);
#pragma unroll
      for (int j = 0; j < 4; ++j)
        acc[j] = fmaf(w, (float)hv[j] + (float)lv[j], acc[j]);
    }
    __syncthreads();
  }
#pragma unroll
  for (int j = 0; j < 4; ++j) pooled[(size_t)g * NPROJ + 4 * t + j] = acc[j];
}

__global__ __launch_bounds__(256) void k_cls1(const float* __restrict__ pooled,
                                              const float* __restrict__ W1,
                                              const float* __restrict__ b1,
                                              float* __restrict__ hid) {
  __shared__ float p[1024];
  int g = blockIdx.y;
  int colc = blockIdx.x * 256 + threadIdx.x;
  for (int k = threadIdx.x; k < 1024; k += 256) p[k] = pooled[(size_t)g * 1024 + k];
  __syncthreads();
  float s = 0.f;
  for (int k = 0; k < 1024; ++k) s = fmaf(p[k], W1[(size_t)k * 512 + colc], s);
  s += b1[colc];
  s = 0.5f * s * (1.f + erff(s * 0.70710678118654752f));
  hid[(size_t)g * 512 + colc] = s;
}

__global__ void k_cls2(const float* __restrict__ hid,
                       const float* __restrict__ W2,
                       const float* __restrict__ b2, float* __restrict__ out) {
  int o = blockIdx.x, g = blockIdx.y, lane = threadIdx.x;
  float s = 0.f;
  for (int k = lane; k < 512; k += 64) s = fmaf(hid[(size_t)g * 512 + k], W2[k * 14 + o], s);
  for (int off = 32; off > 0; off >>= 1) s += __shfl_down(s, off);
  if (lane == 0) out[g * 14 + o] = s + b2[o];
}

// ============================================================
extern "C" void kernel_launch(void* const* d_in, const int* in_sizes, int n_in,
                              void* d_out, int out_size, void* d_ws, size_t ws_size,
                              hipStream_t stream) {
  const float* x_in   = (const float*)d_in[0];
  const int*   eidx   = (const int*)d_in[1];
  const int*   batch  = (const int*)d_in[2];
  const float* proj_W = (const float*)d_in[3];
  const float* proj_b = (const float*)d_in[4];
  const float* gat_W  = (const float*)d_in[5];
  const float* a_src  = (const float*)d_in[6];
  const float* a_dst  = (const float*)d_in[7];
  const float* gat_b  = (const float*)d_in[8];
  const float* gamma  = (const float*)d_in[9];
  const float* beta   = (const float*)d_in[10];
  const float* pW1    = (const float*)d_in[11];
  const float* pb1    = (const float*)d_in[12];
  const float* pW2    = (const float*)d_in[13];
  const float* pb2    = (const float*)d_in[14];
  const float* cW1    = (const float*)d_in[15];
  const float* cb1    = (const float*)d_in[16];
  const float* cW2    = (const float*)d_in[17];
  const float* cb2    = (const float*)d_in[18];
  float* out = (float*)d_out;

  const int N = in_sizes[0] / NPROJ;  // 10000
  const int E = in_sizes[1] / 2;      // 160000
  const int Etot = E + N;

  char* ws = (char*)d_ws;
  size_t off = 0;
  auto alloc = [&](size_t bytes) -> void* {
    void* p = ws + off;
    off = (off + bytes + 255) & ~(size_t)255;
    return p;
  };
  _Float16* xh   = (_Float16*)alloc((size_t)N * NPROJ * 2);
  _Float16* xl   = (_Float16*)alloc((size_t)N * NPROJ * 2);
  _Float16* hf   = (_Float16*)alloc((size_t)N * NPROJ * 2);   // f16 h
  float*    hb   = (float*)alloc((size_t)N * NPROJ * 4);      // in-split / tb
  _Float16* pjh  = (_Float16*)alloc((size_t)NPROJ * NPROJ * 2);
  _Float16* pjl  = (_Float16*)alloc((size_t)NPROJ * NPROJ * 2);
  _Float16* gwh  = (_Float16*)alloc((size_t)3 * NPROJ * NPROJ * 2);
  _Float16* gwl  = (_Float16*)alloc((size_t)3 * NPROJ * NPROJ * 2);
  _Float16* pwh  = (_Float16*)alloc((size_t)512 * NPROJ * 2);
  _Float16* pwl  = (_Float16*)alloc((size_t)512 * NPROJ * 2);
  float* asb     = (float*)alloc((size_t)N * 4 * 4);
  float* adb     = (float*)alloc((size_t)N * 4 * 4);
  int*   cnt     = (int*)alloc((size_t)N * 4);
  int*   rowst   = (int*)alloc((size_t)(N + 1) * 4);
  int*   cursor  = (int*)alloc((size_t)N * 4);
  int*   ccol    = (int*)alloc((size_t)Etot * 4);
  float* scores  = (float*)alloc((size_t)N * 4);
  int*   gstart  = (int*)alloc(NGRAPH * 4);
  int*   gend    = (int*)alloc(NGRAPH * 4);
  float* pooled  = (float*)alloc((size_t)NGRAPH * NPROJ * 4);
  float* hid     = (float*)alloc((size_t)NGRAPH * 512 * 4);

  const int* esrc = eidx;
  const int* edst = eidx + E;

  // ---- CSR by dst ----
  k_init_counts<<<(N + 255) / 256, 256, 0, stream>>>(cnt, N);
  k_count<<<(E + 255) / 256, 256, 0, stream>>>(edst, cnt, E);
  k_scan<<<1, 1024, 0, stream>>>(cnt, rowst, cursor, N);
  k_fill<<<(E + 255) / 256, 256, 0, stream>>>(esrc, edst, cursor, ccol, E);
  k_fill_self<<<(N + 255) / 256, 256, 0, stream>>>(cursor, ccol, N);

  // ---- weight splits (transposed) ----
  k_splitT<<<dim3(32, 32), 256, 0, stream>>>(proj_W, pjh, pjl, NPROJ, NPROJ);
  for (int i = 0; i < 3; ++i)
    k_splitT<<<dim3(32, 32), 256, 0, stream>>>(gat_W + (size_t)i * NPROJ * NPROJ,
                                               gwh + (size_t)i * NPROJ * NPROJ,
                                               gwl + (size_t)i * NPROJ * NPROJ,
                                               NPROJ, NPROJ);
  k_splitT<<<dim3(16, 32), 256, 0, stream>>>(pW1, pwh, pwl, NPROJ, 512);

  // ---- input split (scratch inside hb) + projection ----
  _Float16* inh = (_Float16*)hb;
  _Float16* inl = inh + (size_t)N * NPROJ;
  k_split8<<<((N * NPROJ / 8) + 255) / 256, 256, 0, stream>>>(x_in, inh, inl,
                                                              N * NPROJ / 8);
  const int MB = (N + 127) / 128;       // 79
  const int mpad8 = (MB + 7) / 8;       // 10
  const dim3 grid8(8 * mpad8 * 8);      // Nc=1024: lgn=3
  const dim3 grid4(4 * mpad8 * 8);      // Nc=512:  lgn=2
  gemm_mfma<0, 1><<<grid8, 256, 0, stream>>>(
      inh, inl, pjh, pjl, proj_b, nullptr, xh, xl, N, NPROJ, 3, mpad8);

  // ---- 3 GAT layers ----
  for (int i = 0; i < 3; ++i) {
    gemm_mfma<0, 2><<<grid8, 256, 0, stream>>>(
        xh, xl, gwh + (size_t)i * NPROJ * NPROJ, gwl + (size_t)i * NPROJ * NPROJ,
        nullptr, nullptr, hf, nullptr, N, NPROJ, 3, mpad8);
    k_alpha<<<N, 256, 0, stream>>>(hf, a_src + i * NPROJ, a_dst + i * NPROJ, asb, adb);
    k_aggregate_ln<<<N, 256, 0, stream>>>(hf, asb, adb, rowst, ccol,
                                          gat_b + i * NPROJ, gamma + i * NPROJ,
                                          beta + i * NPROJ, xh, xl);
  }

  // ---- attention pooling ----
  float* tb = hb;  // N x 512 f32
  gemm_mfma<1, 0><<<grid4, 256, 0, stream>>>(
      xh, xl, pwh, pwl, pb1, tb, nullptr, nullptr, N, 512, 2, mpad8);
  k_scores<<<N, 64, 0, stream>>>(tb, pW2, pb2, scores, N);
  k_grange_init<<<1, 64, 0, stream>>>(gstart, gend, N);
  k_grange_mark<<<(N + 255) / 256, 256, 0, stream>>>(batch, gstart, gend, N);
  k_pool<<<NGRAPH, 256, 0, stream>>>(scores, xh, xl, gstart, gend, pooled);

  // ---- classifier ----
  k_cls1<<<dim3(2, NGRAPH), 256, 0, stream>>>(pooled, cW1, cb1, hid);
  k_cls2<<<dim3(14, NGRAPH), 64, 0, stream>>>(hid, cW2, cb2, out);
}

// Round 5
// 756.470 us; speedup vs baseline: 1.7103x; 1.7103x over previous
//
#include <hip/hip_runtime.h>
#include <hip/hip_bf16.h>
#include <hip/hip_fp16.h>
#include <math.h>

#define NPROJ 1024
#define NHEADS 4
#define NHID 256
#define NGRAPH 64

typedef _Float16 half8 __attribute__((ext_vector_type(8)));
typedef _Float16 half4v __attribute__((ext_vector_type(4)));
typedef float floatx4 __attribute__((ext_vector_type(4)));

#define GLD_LDS16(g, l)                                                        \
  __builtin_amdgcn_global_load_lds(                                            \
      (const __attribute__((address_space(1))) unsigned int*)(g),              \
      (__attribute__((address_space(3))) unsigned int*)(l), 16, 0, 0)

// ============================================================
// Split-precision f16 MFMA GEMM (LDS, merged staging, overlapped):
//   C = Ah@BhT^T + Ah@BlT^T + Al@BhT^T   (K fixed = 1024)
// A: M x 1024 row-major (hi/lo f16).  B TRANSPOSED: Nc x 1024 (hi/lo).
// 128x128 tile, BK=64, 4 waves (2x2), wave 64x64, 16x16x32 MFMA.
// Single 64KB LDS buffer; per tile: read ALL fragments to regs, barrier,
// then issue next tile's global_load_lds UNDER the 48 remaining MFMAs
// (register-held fragments make the single buffer safe to overwrite).
// XOR-swizzled LDS via pre-swizzled global source (both-sides rule).
// XCD-chunked grid: each XCD owns mpad8 contiguous row-slabs, bx fastest.
// ============================================================
template<int ACT, int OUT>  // ACT: 0 none, 1 tanh; OUT: 0 f32, 1 split pair, 2 f16
__global__ __launch_bounds__(256) void gemm_mfma(
    const _Float16* __restrict__ Ah, const _Float16* __restrict__ Al,
    const _Float16* __restrict__ BhT, const _Float16* __restrict__ BlT,
    const float* __restrict__ bias, float* __restrict__ Cf,
    _Float16* __restrict__ Ch, _Float16* __restrict__ Cl,
    int M, int Nc, int lgn, int mpad8)
{
  __shared__ __align__(16) _Float16 ldsAh[128 * 64];
  __shared__ __align__(16) _Float16 ldsAl[128 * 64];
  __shared__ __align__(16) _Float16 ldsBh[128 * 64];
  __shared__ __align__(16) _Float16 ldsBl[128 * 64];

  const int id  = blockIdx.x;
  const int xcd = id & 7;
  const int kk  = id >> 3;
  const int bx  = kk & ((1 << lgn) - 1);
  const int by  = xcd * mpad8 + (kk >> lgn);
  const int m0  = by * 128, n0 = bx * 128;
  if (m0 >= M) return;

  const int tid  = threadIdx.x;
  const int lane = tid & 63;
  const int wave = tid >> 6;
  const int wm = wave >> 1, wn = wave & 1;

  // staging: chunk ci = r*256 + tid covers LDS bytes ci*16.
  // row = ci>>3, phys chunk-in-row = ci&7, stored logical k-chunk =
  // (ci&7) ^ (row&7)  (XOR swizzle involution)
  const int srow = tid >> 3;                              // + r*32
  const int kc8  = (((tid & 7) ^ ((tid >> 3) & 7)) << 3); // logical k elems
  const int wb16 = (tid & ~63) * 16;                      // wave-uniform base

  floatx4 acc[4][4] = {};

  const int l15 = lane & 15;
  const int swz = (l15 & 7) << 4;
  const int kbyte0 = (lane >> 4) * 16;

  auto STAGE = [&](int t) {
    const int k0 = t << 6;
#pragma unroll
    for (int r = 0; r < 4; ++r) {
      int rowA = m0 + r * 32 + srow;
      rowA = rowA < M ? rowA : (M - 1);
      const size_t aoff = (size_t)rowA * 1024 + k0 + kc8;
      GLD_LDS16(Ah + aoff, (char*)ldsAh + r * 4096 + wb16);
      GLD_LDS16(Al + aoff, (char*)ldsAl + r * 4096 + wb16);
      const size_t boff = (size_t)(n0 + r * 32 + srow) * 1024 + k0 + kc8;
      GLD_LDS16(BhT + boff, (char*)ldsBh + r * 4096 + wb16);
      GLD_LDS16(BlT + boff, (char*)ldsBl + r * 4096 + wb16);
    }
  };

  STAGE(0);
  __syncthreads();

  for (int t = 0; t < 16; ++t) {
    // ---- ks=0 fragments -> regs ----
    const int koff0 = kbyte0 ^ swz;
    half8 ah0[4], bh0[4], al0[4], bl0[4];
#pragma unroll
    for (int i = 0; i < 4; ++i) {
      const int rb = (wm * 64 + i * 16 + l15) * 128;
      ah0[i] = *(const half8*)((const char*)ldsAh + rb + koff0);
      al0[i] = *(const half8*)((const char*)ldsAl + rb + koff0);
    }
#pragma unroll
    for (int j = 0; j < 4; ++j) {
      const int rb = (wn * 64 + j * 16 + l15) * 128;
      bh0[j] = *(const half8*)((const char*)ldsBh + rb + koff0);
      bl0[j] = *(const half8*)((const char*)ldsBl + rb + koff0);
    }
    // ---- 48 MFMAs on ks=0 ----
#pragma unroll
    for (int i = 0; i < 4; ++i)
#pragma unroll
      for (int j = 0; j < 4; ++j)
        acc[i][j] = __builtin_amdgcn_mfma_f32_16x16x32_f16(ah0[i], bh0[j],
                                                           acc[i][j], 0, 0, 0);
#pragma unroll
    for (int i = 0; i < 4; ++i)
#pragma unroll
      for (int j = 0; j < 4; ++j)
        acc[i][j] = __builtin_amdgcn_mfma_f32_16x16x32_f16(ah0[i], bl0[j],
                                                           acc[i][j], 0, 0, 0);
#pragma unroll
    for (int i = 0; i < 4; ++i)
#pragma unroll
      for (int j = 0; j < 4; ++j)
        acc[i][j] = __builtin_amdgcn_mfma_f32_16x16x32_f16(al0[i], bh0[j],
                                                           acc[i][j], 0, 0, 0);

    // ---- ks=1 fragments -> regs ----
    const int koff1 = (64 + kbyte0) ^ swz;
    half8 ah1[4], bh1[4], al1[4], bl1[4];
#pragma unroll
    for (int i = 0; i < 4; ++i) {
      const int rb = (wm * 64 + i * 16 + l15) * 128;
      ah1[i] = *(const half8*)((const char*)ldsAh + rb + koff1);
      al1[i] = *(const half8*)((const char*)ldsAl + rb + koff1);
    }
#pragma unroll
    for (int j = 0; j < 4; ++j) {
      const int rb = (wn * 64 + j * 16 + l15) * 128;
      bh1[j] = *(const half8*)((const char*)ldsBh + rb + koff1);
      bl1[j] = *(const half8*)((const char*)ldsBl + rb + koff1);
    }
    __syncthreads();            // all LDS reads of tile t complete (regs held)
    if (t < 15) STAGE(t + 1);   // overwrite LDS under the MFMAs below

    // ---- 48 MFMAs on ks=1 ----
#pragma unroll
    for (int i = 0; i < 4; ++i)
#pragma unroll
      for (int j = 0; j < 4; ++j)
        acc[i][j] = __builtin_amdgcn_mfma_f32_16x16x32_f16(ah1[i], bh1[j],
                                                           acc[i][j], 0, 0, 0);
#pragma unroll
    for (int i = 0; i < 4; ++i)
#pragma unroll
      for (int j = 0; j < 4; ++j)
        acc[i][j] = __builtin_amdgcn_mfma_f32_16x16x32_f16(ah1[i], bl1[j],
                                                           acc[i][j], 0, 0, 0);
#pragma unroll
    for (int i = 0; i < 4; ++i)
#pragma unroll
      for (int j = 0; j < 4; ++j)
        acc[i][j] = __builtin_amdgcn_mfma_f32_16x16x32_f16(al1[i], bh1[j],
                                                           acc[i][j], 0, 0, 0);

    if (t < 15) __syncthreads();  // vmcnt drain (mostly hidden by MFMAs)
  }

  // epilogue: C[row = (lane>>4)*4 + reg, col = lane&15] per 16x16 frag
  const int rbase = (lane >> 4) * 4;
#pragma unroll
  for (int j = 0; j < 4; ++j) {
    const int col = n0 + wn * 64 + j * 16 + l15;
    const float bv = bias ? bias[col] : 0.f;
#pragma unroll
    for (int i = 0; i < 4; ++i) {
      const int gm0 = m0 + wm * 64 + i * 16 + rbase;
#pragma unroll
      for (int r = 0; r < 4; ++r) {
        const int gm = gm0 + r;
        if (gm >= M) continue;
        float v = acc[i][j][r] + bv;
        if (ACT == 1) v = tanhf(v);
        if (OUT == 1) {
          _Float16 hh = (_Float16)v;
          Ch[(size_t)gm * Nc + col] = hh;
          Cl[(size_t)gm * Nc + col] = (_Float16)(v - (float)hh);
        } else if (OUT == 2) {
          Ch[(size_t)gm * Nc + col] = (_Float16)v;
        } else {
          Cf[(size_t)gm * Nc + col] = v;
        }
      }
    }
  }
}

// ============================================================
// splitters
// ============================================================
__global__ void k_split8(const float* __restrict__ in, _Float16* __restrict__ h,
                         _Float16* __restrict__ l, int L8) {
  int i = blockIdx.x * 256 + threadIdx.x;
  if (i >= L8) return;
  const float4* p = (const float4*)(in + (size_t)i * 8);
  float4 v0 = p[0], v1 = p[1];
  float vv[8] = {v0.x, v0.y, v0.z, v0.w, v1.x, v1.y, v1.z, v1.w};
  half8 hv, lv;
#pragma unroll
  for (int j = 0; j < 8; ++j) {
    _Float16 hh = (_Float16)vv[j];
    hv[j] = hh;
    lv[j] = (_Float16)(vv[j] - (float)hh);
  }
  *(half8*)(h + (size_t)i * 8) = hv;
  *(half8*)(l + (size_t)i * 8) = lv;
}

// W (K x Nc) fp32 -> transposed split (Nc x K) f16 hi/lo
__global__ __launch_bounds__(256) void k_splitT(const float* __restrict__ in,
                                                _Float16* __restrict__ hT,
                                                _Float16* __restrict__ lT,
                                                int K, int Nc) {
  __shared__ float t[32][33];
  const int tx = threadIdx.x & 31, ty = threadIdx.x >> 5;
  const int c0 = blockIdx.x * 32, k0 = blockIdx.y * 32;
#pragma unroll
  for (int r = 0; r < 4; ++r)
    t[ty + 8 * r][tx] = in[(size_t)(k0 + ty + 8 * r) * Nc + c0 + tx];
  __syncthreads();
#pragma unroll
  for (int r = 0; r < 4; ++r) {
    float v = t[tx][ty + 8 * r];
    int oc = c0 + ty + 8 * r;
    _Float16 hh = (_Float16)v;
    hT[(size_t)oc * K + k0 + tx] = hh;
    lT[(size_t)oc * K + k0 + tx] = (_Float16)(v - (float)hh);
  }
}

// ============================================================
// CSR-by-dst construction (recomputed every call; no caching)
// ============================================================
__global__ void k_init_counts(int* cnt, int n) {
  int i = blockIdx.x * 256 + threadIdx.x;
  if (i < n) cnt[i] = 1;  // self-loop pre-counted
}

__global__ void k_count(const int* __restrict__ dst, int* cnt, int e) {
  int i = blockIdx.x * 256 + threadIdx.x;
  if (i < e) atomicAdd(&cnt[dst[i]], 1);
}

__global__ __launch_bounds__(1024) void k_scan(const int* __restrict__ cnt,
                                               int* __restrict__ rowstart,
                                               int* __restrict__ cursor, int n) {
  __shared__ int buf[1024];
  __shared__ int carry;
  int t = threadIdx.x;
  if (t == 0) carry = 0;
  __syncthreads();
  for (int base = 0; base < n; base += 1024) {
    int x = (base + t < n) ? cnt[base + t] : 0;
    buf[t] = x;
    __syncthreads();
    for (int off = 1; off < 1024; off <<= 1) {
      int v = (t >= off) ? buf[t - off] : 0;
      __syncthreads();
      buf[t] += v;
      __syncthreads();
    }
    int c0 = carry;
    int excl = buf[t] - x + c0;
    if (base + t < n) { rowstart[base + t] = excl; cursor[base + t] = excl; }
    __syncthreads();
    if (t == 0) carry = c0 + buf[1023];
    __syncthreads();
  }
  if (t == 0) rowstart[n] = carry;
}

__global__ void k_fill(const int* __restrict__ src, const int* __restrict__ dst,
                       int* cursor, int* __restrict__ col, int e) {
  int i = blockIdx.x * 256 + threadIdx.x;
  if (i < e) {
    int p = atomicAdd(&cursor[dst[i]], 1);
    col[p] = src[i];
  }
}

__global__ void k_fill_self(int* cursor, int* __restrict__ col, int n) {
  int i = blockIdx.x * 256 + threadIdx.x;
  if (i < n) {
    int p = atomicAdd(&cursor[i], 1);
    col[p] = i;
  }
}

// ============================================================
// per-node attention logits (f16 h): one wave per head
// ============================================================
__global__ __launch_bounds__(256) void k_alpha(
    const _Float16* __restrict__ h, const float* __restrict__ a_src,
    const float* __restrict__ a_dst, float* __restrict__ as_out,
    float* __restrict__ ad_out) {
  int n = blockIdx.x, t = threadIdx.x;
  const int wv = t >> 6, ln = t & 63;     // wave = head
  const int cb = wv * 256 + 4 * ln;
  half4v v = *(const half4v*)(h + (size_t)n * NPROJ + cb);
  float4 s4 = *(const float4*)(a_src + cb);
  float4 d4 = *(const float4*)(a_dst + cb);
  float vv[4] = {(float)v[0], (float)v[1], (float)v[2], (float)v[3]};
  float ss = vv[0] * s4.x + vv[1] * s4.y + vv[2] * s4.z + vv[3] * s4.w;
  float sd = vv[0] * d4.x + vv[1] * d4.y + vv[2] * d4.z + vv[3] * d4.w;
#pragma unroll
  for (int off = 32; off > 0; off >>= 1) {
    ss += __shfl_down(ss, off);
    sd += __shfl_down(sd, off);
  }
  if (ln == 0) {
    as_out[n * 4 + wv] = ss;
    ad_out[n * 4 + wv] = sd;
  }
}

// ============================================================
// fused segment-softmax + aggregation (f16 h, 2 edges/iter)
//        + bias + ELU + residual + LayerNorm
// ============================================================
__device__ __forceinline__ float lrelu02(float x) {
  return x > 0.f ? x : 0.2f * x;
}

__global__ __launch_bounds__(256) void k_aggregate_ln(
    const _Float16* __restrict__ h, const float* __restrict__ as_,
    const float* __restrict__ ad_, const int* __restrict__ rowstart,
    const int* __restrict__ col, const float* __restrict__ bias,
    const float* __restrict__ gamma, const float* __restrict__ beta,
    _Float16* __restrict__ xh, _Float16* __restrict__ xl) {
  __shared__ float redm[4][256];
  __shared__ float wts[256][4];
  __shared__ int scol[256];
  __shared__ float combo[128][8];
  __shared__ float Mh[4], Sh[4];
  __shared__ float mu_s, rstd_s;

  int n = blockIdx.x, t = threadIdx.x;
  int rs = rowstart[n], re = rowstart[n + 1];
  float4 ad4 = *(const float4*)(ad_ + n * 4);
  float adn[4] = {ad4.x, ad4.y, ad4.z, ad4.w};

  // pass 1: per-head max
  float mx[4] = {-1e30f, -1e30f, -1e30f, -1e30f};
  for (int e = rs + t; e < re; e += 256) {
    int s = col[e];
    float4 a4 = *(const float4*)(as_ + (size_t)s * 4);
    float av[4] = {a4.x, a4.y, a4.z, a4.w};
#pragma unroll
    for (int j = 0; j < 4; ++j)
      mx[j] = fmaxf(mx[j], lrelu02(av[j] + adn[j]));
  }
#pragma unroll
  for (int j = 0; j < 4; ++j) redm[j][t] = mx[j];
  __syncthreads();
  for (int s = 128; s > 0; s >>= 1) {
    if (t < s)
#pragma unroll
      for (int j = 0; j < 4; ++j)
        redm[j][t] = fmaxf(redm[j][t], redm[j][t + s]);
    __syncthreads();
  }
  if (t < 4) Mh[t] = redm[t][0];
  __syncthreads();
  float M_[4];
#pragma unroll
  for (int j = 0; j < 4; ++j) M_[j] = Mh[j];
  __syncthreads();

  // pass 2: sum of exp
  float sm[4] = {0.f, 0.f, 0.f, 0.f};
  for (int e = rs + t; e < re; e += 256) {
    int s = col[e];
    float4 a4 = *(const float4*)(as_ + (size_t)s * 4);
    float av[4] = {a4.x, a4.y, a4.z, a4.w};
#pragma unroll
    for (int j = 0; j < 4; ++j)
      sm[j] += expf(lrelu02(av[j] + adn[j]) - M_[j]);
  }
#pragma unroll
  for (int j = 0; j < 4; ++j) redm[j][t] = sm[j];
  __syncthreads();
  for (int s = 128; s > 0; s >>= 1) {
    if (t < s)
#pragma unroll
      for (int j = 0; j < 4; ++j) redm[j][t] += redm[j][t + s];
    __syncthreads();
  }
  if (t < 4) Sh[t] = redm[t][0];
  __syncthreads();
  float S_[4];
#pragma unroll
  for (int j = 0; j < 4; ++j) S_[j] = Sh[j] + 1e-16f;
  __syncthreads();

  // pass 3: weighted aggregation; group g over edges, 8 f16 cols per thread
  const int g = t >> 7, c = t & 127;
  const int hd = c >> 5;
  float acc8[8] = {};
  for (int c0 = rs; c0 < re; c0 += 256) {
    int cnt = min(256, re - c0);
    if (t < cnt) {
      int s = col[c0 + t];
      scol[t] = s;
      float4 a4 = *(const float4*)(as_ + (size_t)s * 4);
      float av[4] = {a4.x, a4.y, a4.z, a4.w};
#pragma unroll
      for (int j = 0; j < 4; ++j)
        wts[t][j] = expf(lrelu02(av[j] + adn[j]) - M_[j]) / S_[j];
    }
    __syncthreads();
    for (int e = g; e < cnt; e += 2) {
      float w = wts[e][hd];
      half8 hv = *(const half8*)(h + (size_t)scol[e] * NPROJ + 8 * c);
#pragma unroll
      for (int j = 0; j < 8; ++j) acc8[j] = fmaf(w, (float)hv[j], acc8[j]);
    }
    __syncthreads();
  }
  // combine the two edge-groups
  if (g == 1) {
#pragma unroll
    for (int j = 0; j < 8; ++j) combo[c][j] = acc8[j];
  }
  __syncthreads();
  if (g == 0) {
#pragma unroll
    for (int j = 0; j < 8; ++j) acc8[j] += combo[c][j];
  }

  // epilogue: bias, ELU, residual, LayerNorm (t<128 own cols 8c..8c+7)
  const size_t base = (size_t)n * NPROJ + 8 * c;
  float v[8];
  float sum = 0.f, sumsq = 0.f;
  if (g == 0) {
    float4 b0 = *(const float4*)(bias + 8 * c);
    float4 b1 = *(const float4*)(bias + 8 * c + 4);
    float bvv[8] = {b0.x, b0.y, b0.z, b0.w, b1.x, b1.y, b1.z, b1.w};
    half8 xhv = *(const half8*)(xh + base);
    half8 xlv = *(const half8*)(xl + base);
#pragma unroll
    for (int j = 0; j < 8; ++j) {
      float u = acc8[j] + bvv[j];
      u = u > 0.f ? u : expm1f(u);
      u += (float)xhv[j] + (float)xlv[j];
      v[j] = u;
      sum += u;
      sumsq += u * u;
    }
  }
  redm[0][t] = g == 0 ? sum : 0.f;
  redm[1][t] = g == 0 ? sumsq : 0.f;
  __syncthreads();
  for (int s = 64; s > 0; s >>= 1) {
    if (t < s) {
      redm[0][t] += redm[0][t + s];
      redm[1][t] += redm[1][t + s];
    }
    __syncthreads();
  }
  if (t == 0) {
    float mu = redm[0][0] * (1.f / 1024.f);
    float var = redm[1][0] * (1.f / 1024.f) - mu * mu;
    mu_s = mu;
    rstd_s = rsqrtf(var + 1e-5f);
  }
  __syncthreads();
  if (g == 0) {
    float mu = mu_s, rstd = rstd_s;
    float4 g0 = *(const float4*)(gamma + 8 * c);
    float4 g1 = *(const float4*)(gamma + 8 * c + 4);
    float4 e0 = *(const float4*)(beta + 8 * c);
    float4 e1 = *(const float4*)(beta + 8 * c + 4);
    float gvv[8] = {g0.x, g0.y, g0.z, g0.w, g1.x, g1.y, g1.z, g1.w};
    float bev[8] = {e0.x, e0.y, e0.z, e0.w, e1.x, e1.y, e1.z, e1.w};
    half8 oh, ol;
#pragma unroll
    for (int j = 0; j < 8; ++j) {
      float y = (v[j] - mu) * rstd * gvv[j] + bev[j];
      _Float16 hh = (_Float16)y;
      oh[j] = hh;
      ol[j] = (_Float16)(y - (float)hh);
    }
    *(half8*)(xh + base) = oh;
    *(half8*)(xl + base) = ol;
  }
}

// ============================================================
// pooling + classifier
// ============================================================
__global__ void k_scores(const float* __restrict__ tb,
                         const float* __restrict__ W2,
                         const float* __restrict__ b2,
                         float* __restrict__ scores, int N) {
  int n = blockIdx.x, lane = threadIdx.x;
  float s = 0.f;
  for (int k = lane; k < 512; k += 64) s = fmaf(tb[(size_t)n * 512 + k], W2[k], s);
  for (int off = 32; off > 0; off >>= 1) s += __shfl_down(s, off);
  if (lane == 0) scores[n] = s + b2[0];
}

__global__ void k_grange_init(int* gstart, int* gend, int N) {
  int g = threadIdx.x;
  if (g < NGRAPH) { gstart[g] = N; gend[g] = 0; }
}

__global__ void k_grange_mark(const int* __restrict__ batch, int* gstart,
                              int* gend, int N) {
  int n = blockIdx.x * 256 + threadIdx.x;
  if (n >= N) return;
  int b = batch[n];
  if (n == 0 || batch[n - 1] != b) gstart[b] = n;
  if (n == N - 1 || batch[n + 1] != b) gend[b] = n + 1;
}

__global__ __launch_bounds__(256) void k_pool(
    const float* __restrict__ scores, const _Float16* __restrict__ xh,
    const _Float16* __restrict__ xl, const int* __restrict__ gstart,
    const int* __restrict__ gend, float* __restrict__ pooled) {
  __shared__ float red[256];
  __shared__ float wt[256];
  __shared__ float m_s, s_s;
  int g = blockIdx.x, t = threadIdx.x;
  int rs = gstart[g], re = gend[g];

  float mx = -1e30f;
  for (int i = rs + t; i < re; i += 256) mx = fmaxf(mx, scores[i]);
  red[t] = mx;
  __syncthreads();
  for (int s = 128; s > 0; s >>= 1) {
    if (t < s) red[t] = fmaxf(red[t], red[t + s]);
    __syncthreads();
  }
  if (t == 0) m_s = red[0];
  __syncthreads();
  float m = m_s;

  float sm = 0.f;
  for (int i = rs + t; i < re; i += 256) sm += expf(scores[i] - m);
  red[t] = sm;
  __syncthreads();
  for (int s = 128; s > 0; s >>= 1) {
    if (t < s) red[t] += red[t + s];
    __syncthreads();
  }
  if (t == 0) s_s = red[0] + 1e-16f;
  __syncthreads();
  float sden = s_s;

  float acc[4] = {0.f, 0.f, 0.f, 0.f};
  for (int c0 = rs; c0 < re; c0 += 256) {
    int cnt = min(256, re - c0);
    if (t < cnt) wt[t] = expf(scores[c0 + t] - m) / sden;
    __syncthreads();
    for (int e = 0; e < cnt; ++e) {
      float w = wt[e];
      size_t base = (size_t)(c0 + e) * NPROJ + 4 * t;
      half4v hv = *(const half4v*)(xh + base);
      half4v lv = *(const half4v*)(xl + base);
#pragma unroll
      for (int j = 0; j < 4; ++j)
        acc[j] = fmaf(w, (float)hv[j] + (float)lv[j], acc[j]);
    }
    __syncthreads();
  }
#pragma unroll
  for (int j = 0; j < 4; ++j) pooled[(size_t)g * NPROJ + 4 * t + j] = acc[j];
}

__global__ __launch_bounds__(256) void k_cls1(const float* __restrict__ pooled,
                                              const float* __restrict__ W1,
                                              const float* __restrict__ b1,
                                              float* __restrict__ hid) {
  __shared__ float p[1024];
  int g = blockIdx.y;
  int colc = blockIdx.x * 256 + threadIdx.x;
  for (int k = threadIdx.x; k < 1024; k += 256) p[k] = pooled[(size_t)g * 1024 + k];
  __syncthreads();
  float s = 0.f;
  for (int k = 0; k < 1024; ++k) s = fmaf(p[k], W1[(size_t)k * 512 + colc], s);
  s += b1[colc];
  s = 0.5f * s * (1.f + erff(s * 0.70710678118654752f));
  hid[(size_t)g * 512 + colc] = s;
}

__global__ void k_cls2(const float* __restrict__ hid,
                       const float* __restrict__ W2,
                       const float* __restrict__ b2, float* __restrict__ out) {
  int o = blockIdx.x, g = blockIdx.y, lane = threadIdx.x;
  float s = 0.f;
  for (int k = lane; k < 512; k += 64) s = fmaf(hid[(size_t)g * 512 + k], W2[k * 14 + o], s);
  for (int off = 32; off > 0; off >>= 1) s += __shfl_down(s, off);
  if (lane == 0) out[g * 14 + o] = s + b2[o];
}

// ============================================================
extern "C" void kernel_launch(void* const* d_in, const int* in_sizes, int n_in,
                              void* d_out, int out_size, void* d_ws, size_t ws_size,
                              hipStream_t stream) {
  const float* x_in   = (const float*)d_in[0];
  const int*   eidx   = (const int*)d_in[1];
  const int*   batch  = (const int*)d_in[2];
  const float* proj_W = (const float*)d_in[3];
  const float* proj_b = (const float*)d_in[4];
  const float* gat_W  = (const float*)d_in[5];
  const float* a_src  = (const float*)d_in[6];
  const float* a_dst  = (const float*)d_in[7];
  const float* gat_b  = (const float*)d_in[8];
  const float* gamma  = (const float*)d_in[9];
  const float* beta   = (const float*)d_in[10];
  const float* pW1    = (const float*)d_in[11];
  const float* pb1    = (const float*)d_in[12];
  const float* pW2    = (const float*)d_in[13];
  const float* pb2    = (const float*)d_in[14];
  const float* cW1    = (const float*)d_in[15];
  const float* cb1    = (const float*)d_in[16];
  const float* cW2    = (const float*)d_in[17];
  const float* cb2    = (const float*)d_in[18];
  float* out = (float*)d_out;

  const int N = in_sizes[0] / NPROJ;  // 10000
  const int E = in_sizes[1] / 2;      // 160000
  const int Etot = E + N;

  char* ws = (char*)d_ws;
  size_t off = 0;
  auto alloc = [&](size_t bytes) -> void* {
    void* p = ws + off;
    off = (off + bytes + 255) & ~(size_t)255;
    return p;
  };
  _Float16* xh   = (_Float16*)alloc((size_t)N * NPROJ * 2);
  _Float16* xl   = (_Float16*)alloc((size_t)N * NPROJ * 2);
  _Float16* hf   = (_Float16*)alloc((size_t)N * NPROJ * 2);   // f16 h
  float*    hb   = (float*)alloc((size_t)N * NPROJ * 4);      // in-split / tb
  _Float16* pjh  = (_Float16*)alloc((size_t)NPROJ * NPROJ * 2);
  _Float16* pjl  = (_Float16*)alloc((size_t)NPROJ * NPROJ * 2);
  _Float16* gwh  = (_Float16*)alloc((size_t)3 * NPROJ * NPROJ * 2);
  _Float16* gwl  = (_Float16*)alloc((size_t)3 * NPROJ * NPROJ * 2);
  _Float16* pwh  = (_Float16*)alloc((size_t)512 * NPROJ * 2);
  _Float16* pwl  = (_Float16*)alloc((size_t)512 * NPROJ * 2);
  float* asb     = (float*)alloc((size_t)N * 4 * 4);
  float* adb     = (float*)alloc((size_t)N * 4 * 4);
  int*   cnt     = (int*)alloc((size_t)N * 4);
  int*   rowst   = (int*)alloc((size_t)(N + 1) * 4);
  int*   cursor  = (int*)alloc((size_t)N * 4);
  int*   ccol    = (int*)alloc((size_t)Etot * 4);
  float* scores  = (float*)alloc((size_t)N * 4);
  int*   gstart  = (int*)alloc(NGRAPH * 4);
  int*   gend    = (int*)alloc(NGRAPH * 4);
  float* pooled  = (float*)alloc((size_t)NGRAPH * NPROJ * 4);
  float* hid     = (float*)alloc((size_t)NGRAPH * 512 * 4);

  const int* esrc = eidx;
  const int* edst = eidx + E;

  // ---- CSR by dst ----
  k_init_counts<<<(N + 255) / 256, 256, 0, stream>>>(cnt, N);
  k_count<<<(E + 255) / 256, 256, 0, stream>>>(edst, cnt, E);
  k_scan<<<1, 1024, 0, stream>>>(cnt, rowst, cursor, N);
  k_fill<<<(E + 255) / 256, 256, 0, stream>>>(esrc, edst, cursor, ccol, E);
  k_fill_self<<<(N + 255) / 256, 256, 0, stream>>>(cursor, ccol, N);

  // ---- weight splits (transposed) ----
  k_splitT<<<dim3(32, 32), 256, 0, stream>>>(proj_W, pjh, pjl, NPROJ, NPROJ);
  for (int i = 0; i < 3; ++i)
    k_splitT<<<dim3(32, 32), 256, 0, stream>>>(gat_W + (size_t)i * NPROJ * NPROJ,
                                               gwh + (size_t)i * NPROJ * NPROJ,
                                               gwl + (size_t)i * NPROJ * NPROJ,
                                               NPROJ, NPROJ);
  k_splitT<<<dim3(16, 32), 256, 0, stream>>>(pW1, pwh, pwl, NPROJ, 512);

  // ---- input split (scratch inside hb) + projection ----
  _Float16* inh = (_Float16*)hb;
  _Float16* inl = inh + (size_t)N * NPROJ;
  k_split8<<<((N * NPROJ / 8) + 255) / 256, 256, 0, stream>>>(x_in, inh, inl,
                                                              N * NPROJ / 8);
  const int MB = (N + 127) / 128;       // 79
  const int mpad8 = (MB + 7) / 8;       // 10
  const dim3 grid8(8 * mpad8 * 8);      // Nc=1024: lgn=3
  const dim3 grid4(4 * mpad8 * 8);      // Nc=512:  lgn=2
  gemm_mfma<0, 1><<<grid8, 256, 0, stream>>>(
      inh, inl, pjh, pjl, proj_b, nullptr, xh, xl, N, NPROJ, 3, mpad8);

  // ---- 3 GAT layers ----
  for (int i = 0; i < 3; ++i) {
    gemm_mfma<0, 2><<<grid8, 256, 0, stream>>>(
        xh, xl, gwh + (size_t)i * NPROJ * NPROJ, gwl + (size_t)i * NPROJ * NPROJ,
        nullptr, nullptr, hf, nullptr, N, NPROJ, 3, mpad8);
    k_alpha<<<N, 256, 0, stream>>>(hf, a_src + i * NPROJ, a_dst + i * NPROJ, asb, adb);
    k_aggregate_ln<<<N, 256, 0, stream>>>(hf, asb, adb, rowst, ccol,
                                          gat_b + i * NPROJ, gamma + i * NPROJ,
                                          beta + i * NPROJ, xh, xl);
  }

  // ---- attention pooling ----
  float* tb = hb;  // N x 512 f32
  gemm_mfma<1, 0><<<grid4, 256, 0, stream>>>(
      xh, xl, pwh, pwl, pb1, tb, nullptr, nullptr, N, 512, 2, mpad8);
  k_scores<<<N, 64, 0, stream>>>(tb, pW2, pb2, scores, N);
  k_grange_init<<<1, 64, 0, stream>>>(gstart, gend, N);
  k_grange_mark<<<(N + 255) / 256, 256, 0, stream>>>(batch, gstart, gend, N);
  k_pool<<<NGRAPH, 256, 0, stream>>>(scores, xh, xl, gstart, gend, pooled);

  // ---- classifier ----
  k_cls1<<<dim3(2, NGRAPH), 256, 0, stream>>>(pooled, cW1, cb1, hid);
  k_cls2<<<dim3(14, NGRAPH), 64, 0, stream>>>(hid, cW2, cb2, out);
}

// Round 6
// 618.759 us; speedup vs baseline: 2.0909x; 1.2226x over previous
//
#include <hip/hip_runtime.h>
#include <hip/hip_bf16.h>
#include <hip/hip_fp16.h>
#include <math.h>

#define NPROJ 1024
#define NHEADS 4
#define NHID 256
#define NGRAPH 64

typedef _Float16 half8 __attribute__((ext_vector_type(8)));
typedef _Float16 half4v __attribute__((ext_vector_type(4)));
typedef float floatx4 __attribute__((ext_vector_type(4)));

#define GLD_LDS16(g, l)                                                        \
  __builtin_amdgcn_global_load_lds(                                            \
      (const __attribute__((address_space(1))) unsigned int*)(g),              \
      (__attribute__((address_space(3))) unsigned int*)(l), 16, 0, 0)

// ============================================================
// 2-product split-precision f16 MFMA GEMM:
//   C = A @ BhT^T + A @ BlT^T     (K fixed = 1024)
// A: M x 1024 f16 (hi of fp32).  B TRANSPOSED split: Nc x 1024 hi/lo f16.
// (dropped Al@Bh term ~1e-4 rms on C -- same scale as the f16-h path.)
// 128x128 tile, BK=64, 4 waves (2x2), wave 64x64, 16x16x32 MFMA.
// LDS = 3 x 16KB = 48KB -> 3 blocks/CU (no dispatch tail at 640 blocks).
// Single-buffer overlap: frags->regs, barrier, STAGE(t+1) under MFMAs.
// XOR-swizzled LDS via pre-swizzled global source.
// XCD-chunked grid: each XCD owns mpad8 contiguous row-slabs, bx fastest.
// ============================================================
template<int ACT, int OUT>  // ACT: 0 none, 1 tanh; OUT: 0 f32, 1 split pair, 2 f16
__global__ __launch_bounds__(256, 3) void gemm_mfma(
    const _Float16* __restrict__ A,
    const _Float16* __restrict__ BhT, const _Float16* __restrict__ BlT,
    const float* __restrict__ bias, float* __restrict__ Cf,
    _Float16* __restrict__ Ch, _Float16* __restrict__ Cl,
    int M, int Nc, int lgn, int mpad8)
{
  __shared__ __align__(16) _Float16 ldsA[128 * 64];
  __shared__ __align__(16) _Float16 ldsBh[128 * 64];
  __shared__ __align__(16) _Float16 ldsBl[128 * 64];

  const int id  = blockIdx.x;
  const int xcd = id & 7;
  const int kk  = id >> 3;
  const int bx  = kk & ((1 << lgn) - 1);
  const int by  = xcd * mpad8 + (kk >> lgn);
  const int m0  = by * 128, n0 = bx * 128;
  if (m0 >= M) return;

  const int tid  = threadIdx.x;
  const int lane = tid & 63;
  const int wave = tid >> 6;
  const int wm = wave >> 1, wn = wave & 1;

  // staging: chunk ci = r*256 + tid covers LDS bytes ci*16.
  // row = ci>>3, phys chunk-in-row = ci&7, stored logical k-chunk =
  // (ci&7) ^ (row&7)  (XOR swizzle involution)
  const int srow = tid >> 3;                              // + r*32
  const int kc8  = (((tid & 7) ^ ((tid >> 3) & 7)) << 3); // logical k elems
  const int wb16 = (tid & ~63) * 16;                      // wave-uniform base

  floatx4 acc[4][4] = {};

  const int l15 = lane & 15;
  const int swz = (l15 & 7) << 4;
  const int kbyte0 = (lane >> 4) * 16;

  auto STAGE = [&](int t) {
    const int k0 = t << 6;
#pragma unroll
    for (int r = 0; r < 4; ++r) {
      int rowA = m0 + r * 32 + srow;
      rowA = rowA < M ? rowA : (M - 1);
      GLD_LDS16(A + (size_t)rowA * 1024 + k0 + kc8,
                (char*)ldsA + r * 4096 + wb16);
      const size_t boff = (size_t)(n0 + r * 32 + srow) * 1024 + k0 + kc8;
      GLD_LDS16(BhT + boff, (char*)ldsBh + r * 4096 + wb16);
      GLD_LDS16(BlT + boff, (char*)ldsBl + r * 4096 + wb16);
    }
  };

  STAGE(0);
  __syncthreads();

  for (int t = 0; t < 16; ++t) {
    // ---- ks=0 fragments -> regs ----
    const int koff0 = kbyte0 ^ swz;
    half8 a0[4], bh0[4], bl0[4];
#pragma unroll
    for (int i = 0; i < 4; ++i)
      a0[i] = *(const half8*)((const char*)ldsA +
                              (wm * 64 + i * 16 + l15) * 128 + koff0);
#pragma unroll
    for (int j = 0; j < 4; ++j) {
      const int rb = (wn * 64 + j * 16 + l15) * 128;
      bh0[j] = *(const half8*)((const char*)ldsBh + rb + koff0);
      bl0[j] = *(const half8*)((const char*)ldsBl + rb + koff0);
    }
    // ---- 32 MFMAs on ks=0 ----
#pragma unroll
    for (int i = 0; i < 4; ++i)
#pragma unroll
      for (int j = 0; j < 4; ++j)
        acc[i][j] = __builtin_amdgcn_mfma_f32_16x16x32_f16(a0[i], bh0[j],
                                                           acc[i][j], 0, 0, 0);
#pragma unroll
    for (int i = 0; i < 4; ++i)
#pragma unroll
      for (int j = 0; j < 4; ++j)
        acc[i][j] = __builtin_amdgcn_mfma_f32_16x16x32_f16(a0[i], bl0[j],
                                                           acc[i][j], 0, 0, 0);

    // ---- ks=1 fragments -> regs ----
    const int koff1 = (64 + kbyte0) ^ swz;
    half8 a1[4], bh1[4], bl1[4];
#pragma unroll
    for (int i = 0; i < 4; ++i)
      a1[i] = *(const half8*)((const char*)ldsA +
                              (wm * 64 + i * 16 + l15) * 128 + koff1);
#pragma unroll
    for (int j = 0; j < 4; ++j) {
      const int rb = (wn * 64 + j * 16 + l15) * 128;
      bh1[j] = *(const half8*)((const char*)ldsBh + rb + koff1);
      bl1[j] = *(const half8*)((const char*)ldsBl + rb + koff1);
    }
    __syncthreads();            // all LDS reads of tile t complete (regs held)
    if (t < 15) STAGE(t + 1);   // overwrite LDS under the MFMAs below

    // ---- 32 MFMAs on ks=1 ----
#pragma unroll
    for (int i = 0; i < 4; ++i)
#pragma unroll
      for (int j = 0; j < 4; ++j)
        acc[i][j] = __builtin_amdgcn_mfma_f32_16x16x32_f16(a1[i], bh1[j],
                                                           acc[i][j], 0, 0, 0);
#pragma unroll
    for (int i = 0; i < 4; ++i)
#pragma unroll
      for (int j = 0; j < 4; ++j)
        acc[i][j] = __builtin_amdgcn_mfma_f32_16x16x32_f16(a1[i], bl1[j],
                                                           acc[i][j], 0, 0, 0);

    if (t < 15) __syncthreads();  // vmcnt drain (mostly hidden by MFMAs)
  }

  // epilogue: C[row = (lane>>4)*4 + reg, col = lane&15] per 16x16 frag
  const int rbase = (lane >> 4) * 4;
#pragma unroll
  for (int j = 0; j < 4; ++j) {
    const int col = n0 + wn * 64 + j * 16 + l15;
    const float bv = bias ? bias[col] : 0.f;
#pragma unroll
    for (int i = 0; i < 4; ++i) {
      const int gm0 = m0 + wm * 64 + i * 16 + rbase;
#pragma unroll
      for (int r = 0; r < 4; ++r) {
        const int gm = gm0 + r;
        if (gm >= M) continue;
        float v = acc[i][j][r] + bv;
        if (ACT == 1) v = tanhf(v);
        if (OUT == 1) {
          _Float16 hh = (_Float16)v;
          Ch[(size_t)gm * Nc + col] = hh;
          Cl[(size_t)gm * Nc + col] = (_Float16)(v - (float)hh);
        } else if (OUT == 2) {
          Ch[(size_t)gm * Nc + col] = (_Float16)v;
        } else {
          Cf[(size_t)gm * Nc + col] = v;
        }
      }
    }
  }
}

// ============================================================
// converters
// ============================================================
__global__ void k_tof16(const float* __restrict__ in, _Float16* __restrict__ h,
                        int L8) {
  int i = blockIdx.x * 256 + threadIdx.x;
  if (i >= L8) return;
  const float4* p = (const float4*)(in + (size_t)i * 8);
  float4 v0 = p[0], v1 = p[1];
  float vv[8] = {v0.x, v0.y, v0.z, v0.w, v1.x, v1.y, v1.z, v1.w};
  half8 hv;
#pragma unroll
  for (int j = 0; j < 8; ++j) hv[j] = (_Float16)vv[j];
  *(half8*)(h + (size_t)i * 8) = hv;
}

// W (K x Nc) fp32 -> transposed split (Nc x K) f16 hi/lo
__global__ __launch_bounds__(256) void k_splitT(const float* __restrict__ in,
                                                _Float16* __restrict__ hT,
                                                _Float16* __restrict__ lT,
                                                int K, int Nc) {
  __shared__ float t[32][33];
  const int tx = threadIdx.x & 31, ty = threadIdx.x >> 5;
  const int c0 = blockIdx.x * 32, k0 = blockIdx.y * 32;
#pragma unroll
  for (int r = 0; r < 4; ++r)
    t[ty + 8 * r][tx] = in[(size_t)(k0 + ty + 8 * r) * Nc + c0 + tx];
  __syncthreads();
#pragma unroll
  for (int r = 0; r < 4; ++r) {
    float v = t[tx][ty + 8 * r];
    int oc = c0 + ty + 8 * r;
    _Float16 hh = (_Float16)v;
    hT[(size_t)oc * K + k0 + tx] = hh;
    lT[(size_t)oc * K + k0 + tx] = (_Float16)(v - (float)hh);
  }
}

// ============================================================
// CSR-by-dst construction (recomputed every call; no caching)
// ============================================================
__global__ void k_init_counts(int* cnt, int n) {
  int i = blockIdx.x * 256 + threadIdx.x;
  if (i < n) cnt[i] = 1;  // self-loop pre-counted
}

__global__ void k_count(const int* __restrict__ dst, int* cnt, int e) {
  int i = blockIdx.x * 256 + threadIdx.x;
  if (i < e) atomicAdd(&cnt[dst[i]], 1);
}

__global__ __launch_bounds__(1024) void k_scan(const int* __restrict__ cnt,
                                               int* __restrict__ rowstart,
                                               int* __restrict__ cursor, int n) {
  __shared__ int buf[1024];
  __shared__ int carry;
  int t = threadIdx.x;
  if (t == 0) carry = 0;
  __syncthreads();
  for (int base = 0; base < n; base += 1024) {
    int x = (base + t < n) ? cnt[base + t] : 0;
    buf[t] = x;
    __syncthreads();
    for (int off = 1; off < 1024; off <<= 1) {
      int v = (t >= off) ? buf[t - off] : 0;
      __syncthreads();
      buf[t] += v;
      __syncthreads();
    }
    int c0 = carry;
    int excl = buf[t] - x + c0;
    if (base + t < n) { rowstart[base + t] = excl; cursor[base + t] = excl; }
    __syncthreads();
    if (t == 0) carry = c0 + buf[1023];
    __syncthreads();
  }
  if (t == 0) rowstart[n] = carry;
}

__global__ void k_fill(const int* __restrict__ src, const int* __restrict__ dst,
                       int* cursor, int* __restrict__ col, int e) {
  int i = blockIdx.x * 256 + threadIdx.x;
  if (i < e) {
    int p = atomicAdd(&cursor[dst[i]], 1);
    col[p] = src[i];
  }
}

__global__ void k_fill_self(int* cursor, int* __restrict__ col, int n) {
  int i = blockIdx.x * 256 + threadIdx.x;
  if (i < n) {
    int p = atomicAdd(&cursor[i], 1);
    col[p] = i;
  }
}

// ============================================================
// per-node attention logits (f16 h): one wave per head
// ============================================================
__global__ __launch_bounds__(256) void k_alpha(
    const _Float16* __restrict__ h, const float* __restrict__ a_src,
    const float* __restrict__ a_dst, float* __restrict__ as_out,
    float* __restrict__ ad_out) {
  int n = blockIdx.x, t = threadIdx.x;
  const int wv = t >> 6, ln = t & 63;     // wave = head
  const int cb = wv * 256 + 4 * ln;
  half4v v = *(const half4v*)(h + (size_t)n * NPROJ + cb);
  float4 s4 = *(const float4*)(a_src + cb);
  float4 d4 = *(const float4*)(a_dst + cb);
  float vv[4] = {(float)v[0], (float)v[1], (float)v[2], (float)v[3]};
  float ss = vv[0] * s4.x + vv[1] * s4.y + vv[2] * s4.z + vv[3] * s4.w;
  float sd = vv[0] * d4.x + vv[1] * d4.y + vv[2] * d4.z + vv[3] * d4.w;
#pragma unroll
  for (int off = 32; off > 0; off >>= 1) {
    ss += __shfl_down(ss, off);
    sd += __shfl_down(sd, off);
  }
  if (ln == 0) {
    as_out[n * 4 + wv] = ss;
    ad_out[n * 4 + wv] = sd;
  }
}

// ============================================================
// fused segment-softmax + aggregation (f16 h, 2 edges/iter)
//        + bias + ELU + residual + LayerNorm
// ============================================================
__device__ __forceinline__ float lrelu02(float x) {
  return x > 0.f ? x : 0.2f * x;
}

__global__ __launch_bounds__(256) void k_aggregate_ln(
    const _Float16* __restrict__ h, const float* __restrict__ as_,
    const float* __restrict__ ad_, const int* __restrict__ rowstart,
    const int* __restrict__ col, const float* __restrict__ bias,
    const float* __restrict__ gamma, const float* __restrict__ beta,
    _Float16* __restrict__ xh, _Float16* __restrict__ xl) {
  __shared__ float redm[4][256];
  __shared__ float wts[256][4];
  __shared__ int scol[256];
  __shared__ float combo[128][8];
  __shared__ float Mh[4], Sh[4];
  __shared__ float mu_s, rstd_s;

  int n = blockIdx.x, t = threadIdx.x;
  int rs = rowstart[n], re = rowstart[n + 1];
  float4 ad4 = *(const float4*)(ad_ + n * 4);
  float adn[4] = {ad4.x, ad4.y, ad4.z, ad4.w};

  // pass 1: per-head max
  float mx[4] = {-1e30f, -1e30f, -1e30f, -1e30f};
  for (int e = rs + t; e < re; e += 256) {
    int s = col[e];
    float4 a4 = *(const float4*)(as_ + (size_t)s * 4);
    float av[4] = {a4.x, a4.y, a4.z, a4.w};
#pragma unroll
    for (int j = 0; j < 4; ++j)
      mx[j] = fmaxf(mx[j], lrelu02(av[j] + adn[j]));
  }
#pragma unroll
  for (int j = 0; j < 4; ++j) redm[j][t] = mx[j];
  __syncthreads();
  for (int s = 128; s > 0; s >>= 1) {
    if (t < s)
#pragma unroll
      for (int j = 0; j < 4; ++j)
        redm[j][t] = fmaxf(redm[j][t], redm[j][t + s]);
    __syncthreads();
  }
  if (t < 4) Mh[t] = redm[t][0];
  __syncthreads();
  float M_[4];
#pragma unroll
  for (int j = 0; j < 4; ++j) M_[j] = Mh[j];
  __syncthreads();

  // pass 2: sum of exp
  float sm[4] = {0.f, 0.f, 0.f, 0.f};
  for (int e = rs + t; e < re; e += 256) {
    int s = col[e];
    float4 a4 = *(const float4*)(as_ + (size_t)s * 4);
    float av[4] = {a4.x, a4.y, a4.z, a4.w};
#pragma unroll
    for (int j = 0; j < 4; ++j)
      sm[j] += expf(lrelu02(av[j] + adn[j]) - M_[j]);
  }
#pragma unroll
  for (int j = 0; j < 4; ++j) redm[j][t] = sm[j];
  __syncthreads();
  for (int s = 128; s > 0; s >>= 1) {
    if (t < s)
#pragma unroll
      for (int j = 0; j < 4; ++j) redm[j][t] += redm[j][t + s];
    __syncthreads();
  }
  if (t < 4) Sh[t] = redm[t][0];
  __syncthreads();
  float S_[4];
#pragma unroll
  for (int j = 0; j < 4; ++j) S_[j] = Sh[j] + 1e-16f;
  __syncthreads();

  // pass 3: weighted aggregation; group g over edges, 8 f16 cols per thread
  const int g = t >> 7, c = t & 127;
  const int hd = c >> 5;
  float acc8[8] = {};
  for (int c0 = rs; c0 < re; c0 += 256) {
    int cnt = min(256, re - c0);
    if (t < cnt) {
      int s = col[c0 + t];
      scol[t] = s;
      float4 a4 = *(const float4*)(as_ + (size_t)s * 4);
      float av[4] = {a4.x, a4.y, a4.z, a4.w};
#pragma unroll
      for (int j = 0; j < 4; ++j)
        wts[t][j] = expf(lrelu02(av[j] + adn[j]) - M_[j]) / S_[j];
    }
    __syncthreads();
    for (int e = g; e < cnt; e += 2) {
      float w = wts[e][hd];
      half8 hv = *(const half8*)(h + (size_t)scol[e] * NPROJ + 8 * c);
#pragma unroll
      for (int j = 0; j < 8; ++j) acc8[j] = fmaf(w, (float)hv[j], acc8[j]);
    }
    __syncthreads();
  }
  // combine the two edge-groups
  if (g == 1) {
#pragma unroll
    for (int j = 0; j < 8; ++j) combo[c][j] = acc8[j];
  }
  __syncthreads();
  if (g == 0) {
#pragma unroll
    for (int j = 0; j < 8; ++j) acc8[j] += combo[c][j];
  }

  // epilogue: bias, ELU, residual, LayerNorm (t<128 own cols 8c..8c+7)
  const size_t base = (size_t)n * NPROJ + 8 * c;
  float v[8];
  float sum = 0.f, sumsq = 0.f;
  if (g == 0) {
    float4 b0 = *(const float4*)(bias + 8 * c);
    float4 b1 = *(const float4*)(bias + 8 * c + 4);
    float bvv[8] = {b0.x, b0.y, b0.z, b0.w, b1.x, b1.y, b1.z, b1.w};
    half8 xhv = *(const half8*)(xh + base);
    half8 xlv = *(const half8*)(xl + base);
#pragma unroll
    for (int j = 0; j < 8; ++j) {
      float u = acc8[j] + bvv[j];
      u = u > 0.f ? u : expm1f(u);
      u += (float)xhv[j] + (float)xlv[j];
      v[j] = u;
      sum += u;
      sumsq += u * u;
    }
  }
  redm[0][t] = g == 0 ? sum : 0.f;
  redm[1][t] = g == 0 ? sumsq : 0.f;
  __syncthreads();
  for (int s = 64; s > 0; s >>= 1) {
    if (t < s) {
      redm[0][t] += redm[0][t + s];
      redm[1][t] += redm[1][t + s];
    }
    __syncthreads();
  }
  if (t == 0) {
    float mu = redm[0][0] * (1.f / 1024.f);
    float var = redm[1][0] * (1.f / 1024.f) - mu * mu;
    mu_s = mu;
    rstd_s = rsqrtf(var + 1e-5f);
  }
  __syncthreads();
  if (g == 0) {
    float mu = mu_s, rstd = rstd_s;
    float4 g0 = *(const float4*)(gamma + 8 * c);
    float4 g1 = *(const float4*)(gamma + 8 * c + 4);
    float4 e0 = *(const float4*)(beta + 8 * c);
    float4 e1 = *(const float4*)(beta + 8 * c + 4);
    float gvv[8] = {g0.x, g0.y, g0.z, g0.w, g1.x, g1.y, g1.z, g1.w};
    float bev[8] = {e0.x, e0.y, e0.z, e0.w, e1.x, e1.y, e1.z, e1.w};
    half8 oh, ol;
#pragma unroll
    for (int j = 0; j < 8; ++j) {
      float y = (v[j] - mu) * rstd * gvv[j] + bev[j];
      _Float16 hh = (_Float16)y;
      oh[j] = hh;
      ol[j] = (_Float16)(y - (float)hh);
    }
    *(half8*)(xh + base) = oh;
    *(half8*)(xl + base) = ol;
  }
}

// ============================================================
// pooling + classifier
// ============================================================
__global__ void k_scores(const float* __restrict__ tb,
                         const float* __restrict__ W2,
                         const float* __restrict__ b2,
                         float* __restrict__ scores, int N) {
  int n = blockIdx.x, lane = threadIdx.x;
  float s = 0.f;
  for (int k = lane; k < 512; k += 64) s = fmaf(tb[(size_t)n * 512 + k], W2[k], s);
  for (int off = 32; off > 0; off >>= 1) s += __shfl_down(s, off);
  if (lane == 0) scores[n] = s + b2[0];
}

__global__ void k_grange_init(int* gstart, int* gend, int N) {
  int g = threadIdx.x;
  if (g < NGRAPH) { gstart[g] = N; gend[g] = 0; }
}

__global__ void k_grange_mark(const int* __restrict__ batch, int* gstart,
                              int* gend, int N) {
  int n = blockIdx.x * 256 + threadIdx.x;
  if (n >= N) return;
  int b = batch[n];
  if (n == 0 || batch[n - 1] != b) gstart[b] = n;
  if (n == N - 1 || batch[n + 1] != b) gend[b] = n + 1;
}

__global__ __launch_bounds__(256) void k_pool(
    const float* __restrict__ scores, const _Float16* __restrict__ xh,
    const _Float16* __restrict__ xl, const int* __restrict__ gstart,
    const int* __restrict__ gend, float* __restrict__ pooled) {
  __shared__ float red[256];
  __shared__ float wt[256];
  __shared__ float m_s, s_s;
  int g = blockIdx.x, t = threadIdx.x;
  int rs = gstart[g], re = gend[g];

  float mx = -1e30f;
  for (int i = rs + t; i < re; i += 256) mx = fmaxf(mx, scores[i]);
  red[t] = mx;
  __syncthreads();
  for (int s = 128; s > 0; s >>= 1) {
    if (t < s) red[t] = fmaxf(red[t], red[t + s]);
    __syncthreads();
  }
  if (t == 0) m_s = red[0];
  __syncthreads();
  float m = m_s;

  float sm = 0.f;
  for (int i = rs + t; i < re; i += 256) sm += expf(scores[i] - m);
  red[t] = sm;
  __syncthreads();
  for (int s = 128; s > 0; s >>= 1) {
    if (t < s) red[t] += red[t + s];
    __syncthreads();
  }
  if (t == 0) s_s = red[0] + 1e-16f;
  __syncthreads();
  float sden = s_s;

  float acc[4] = {0.f, 0.f, 0.f, 0.f};
  for (int c0 = rs; c0 < re; c0 += 256) {
    int cnt = min(256, re - c0);
    if (t < cnt) wt[t] = expf(scores[c0 + t] - m) / sden;
    __syncthreads();
    for (int e = 0; e < cnt; ++e) {
      float w = wt[e];
      size_t base = (size_t)(c0 + e) * NPROJ + 4 * t;
      half4v hv = *(const half4v*)(xh + base);
      half4v lv = *(const half4v*)(xl + base);
#pragma unroll
      for (int j = 0; j < 4; ++j)
        acc[j] = fmaf(w, (float)hv[j] + (float)lv[j], acc[j]);
    }
    __syncthreads();
  }
#pragma unroll
  for (int j = 0; j < 4; ++j) pooled[(size_t)g * NPROJ + 4 * t + j] = acc[j];
}

__global__ __launch_bounds__(256) void k_cls1(const float* __restrict__ pooled,
                                              const float* __restrict__ W1,
                                              const float* __restrict__ b1,
                                              float* __restrict__ hid) {
  __shared__ float p[1024];
  int g = blockIdx.y;
  int colc = blockIdx.x * 256 + threadIdx.x;
  for (int k = threadIdx.x; k < 1024; k += 256) p[k] = pooled[(size_t)g * 1024 + k];
  __syncthreads();
  float s = 0.f;
  for (int k = 0; k < 1024; ++k) s = fmaf(p[k], W1[(size_t)k * 512 + colc], s);
  s += b1[colc];
  s = 0.5f * s * (1.f + erff(s * 0.70710678118654752f));
  hid[(size_t)g * 512 + colc] = s;
}

__global__ void k_cls2(const float* __restrict__ hid,
                       const float* __restrict__ W2,
                       const float* __restrict__ b2, float* __restrict__ out) {
  int o = blockIdx.x, g = blockIdx.y, lane = threadIdx.x;
  float s = 0.f;
  for (int k = lane; k < 512; k += 64) s = fmaf(hid[(size_t)g * 512 + k], W2[k * 14 + o], s);
  for (int off = 32; off > 0; off >>= 1) s += __shfl_down(s, off);
  if (lane == 0) out[g * 14 + o] = s + b2[o];
}

// ============================================================
extern "C" void kernel_launch(void* const* d_in, const int* in_sizes, int n_in,
                              void* d_out, int out_size, void* d_ws, size_t ws_size,
                              hipStream_t stream) {
  const float* x_in   = (const float*)d_in[0];
  const int*   eidx   = (const int*)d_in[1];
  const int*   batch  = (const int*)d_in[2];
  const float* proj_W = (const float*)d_in[3];
  const float* proj_b = (const float*)d_in[4];
  const float* gat_W  = (const float*)d_in[5];
  const float* a_src  = (const float*)d_in[6];
  const float* a_dst  = (const float*)d_in[7];
  const float* gat_b  = (const float*)d_in[8];
  const float* gamma  = (const float*)d_in[9];
  const float* beta   = (const float*)d_in[10];
  const float* pW1    = (const float*)d_in[11];
  const float* pb1    = (const float*)d_in[12];
  const float* pW2    = (const float*)d_in[13];
  const float* pb2    = (const float*)d_in[14];
  const float* cW1    = (const float*)d_in[15];
  const float* cb1    = (const float*)d_in[16];
  const float* cW2    = (const float*)d_in[17];
  const float* cb2    = (const float*)d_in[18];
  float* out = (float*)d_out;

  const int N = in_sizes[0] / NPROJ;  // 10000
  const int E = in_sizes[1] / 2;      // 160000
  const int Etot = E + N;

  char* ws = (char*)d_ws;
  size_t off = 0;
  auto alloc = [&](size_t bytes) -> void* {
    void* p = ws + off;
    off = (off + bytes + 255) & ~(size_t)255;
    return p;
  };
  _Float16* xh   = (_Float16*)alloc((size_t)N * NPROJ * 2);
  _Float16* xl   = (_Float16*)alloc((size_t)N * NPROJ * 2);
  _Float16* hf   = (_Float16*)alloc((size_t)N * NPROJ * 2);   // f16 h
  float*    hb   = (float*)alloc((size_t)N * NPROJ * 4);      // in-f16 / tb
  _Float16* pjh  = (_Float16*)alloc((size_t)NPROJ * NPROJ * 2);
  _Float16* pjl  = (_Float16*)alloc((size_t)NPROJ * NPROJ * 2);
  _Float16* gwh  = (_Float16*)alloc((size_t)3 * NPROJ * NPROJ * 2);
  _Float16* gwl  = (_Float16*)alloc((size_t)3 * NPROJ * NPROJ * 2);
  _Float16* pwh  = (_Float16*)alloc((size_t)512 * NPROJ * 2);
  _Float16* pwl  = (_Float16*)alloc((size_t)512 * NPROJ * 2);
  float* asb     = (float*)alloc((size_t)N * 4 * 4);
  float* adb     = (float*)alloc((size_t)N * 4 * 4);
  int*   cnt     = (int*)alloc((size_t)N * 4);
  int*   rowst   = (int*)alloc((size_t)(N + 1) * 4);
  int*   cursor  = (int*)alloc((size_t)N * 4);
  int*   ccol    = (int*)alloc((size_t)Etot * 4);
  float* scores  = (float*)alloc((size_t)N * 4);
  int*   gstart  = (int*)alloc(NGRAPH * 4);
  int*   gend    = (int*)alloc(NGRAPH * 4);
  float* pooled  = (float*)alloc((size_t)NGRAPH * NPROJ * 4);
  float* hid     = (float*)alloc((size_t)NGRAPH * 512 * 4);

  const int* esrc = eidx;
  const int* edst = eidx + E;

  // ---- CSR by dst ----
  k_init_counts<<<(N + 255) / 256, 256, 0, stream>>>(cnt, N);
  k_count<<<(E + 255) / 256, 256, 0, stream>>>(edst, cnt, E);
  k_scan<<<1, 1024, 0, stream>>>(cnt, rowst, cursor, N);
  k_fill<<<(E + 255) / 256, 256, 0, stream>>>(esrc, edst, cursor, ccol, E);
  k_fill_self<<<(N + 255) / 256, 256, 0, stream>>>(cursor, ccol, N);

  // ---- weight splits (transposed) ----
  k_splitT<<<dim3(32, 32), 256, 0, stream>>>(proj_W, pjh, pjl, NPROJ, NPROJ);
  for (int i = 0; i < 3; ++i)
    k_splitT<<<dim3(32, 32), 256, 0, stream>>>(gat_W + (size_t)i * NPROJ * NPROJ,
                                               gwh + (size_t)i * NPROJ * NPROJ,
                                               gwl + (size_t)i * NPROJ * NPROJ,
                                               NPROJ, NPROJ);
  k_splitT<<<dim3(16, 32), 256, 0, stream>>>(pW1, pwh, pwl, NPROJ, 512);

  // ---- input f16 (scratch inside hb) + projection ----
  _Float16* inh = (_Float16*)hb;
  k_tof16<<<((N * NPROJ / 8) + 255) / 256, 256, 0, stream>>>(x_in, inh,
                                                             N * NPROJ / 8);
  const int MB = (N + 127) / 128;       // 79
  const int mpad8 = (MB + 7) / 8;       // 10
  const dim3 grid8(8 * mpad8 * 8);      // Nc=1024: lgn=3
  const dim3 grid4(4 * mpad8 * 8);      // Nc=512:  lgn=2
  gemm_mfma<0, 1><<<grid8, 256, 0, stream>>>(
      inh, pjh, pjl, proj_b, nullptr, xh, xl, N, NPROJ, 3, mpad8);

  // ---- 3 GAT layers ----
  for (int i = 0; i < 3; ++i) {
    gemm_mfma<0, 2><<<grid8, 256, 0, stream>>>(
        xh, gwh + (size_t)i * NPROJ * NPROJ, gwl + (size_t)i * NPROJ * NPROJ,
        nullptr, nullptr, hf, nullptr, N, NPROJ, 3, mpad8);
    k_alpha<<<N, 256, 0, stream>>>(hf, a_src + i * NPROJ, a_dst + i * NPROJ, asb, adb);
    k_aggregate_ln<<<N, 256, 0, stream>>>(hf, asb, adb, rowst, ccol,
                                          gat_b + i * NPROJ, gamma + i * NPROJ,
                                          beta + i * NPROJ, xh, xl);
  }

  // ---- attention pooling ----
  float* tb = hb;  // N x 512 f32
  gemm_mfma<1, 0><<<grid4, 256, 0, stream>>>(
      xh, pwh, pwl, pb1, tb, nullptr, nullptr, N, 512, 2, mpad8);
  k_scores<<<N, 64, 0, stream>>>(tb, pW2, pb2, scores, N);
  k_grange_init<<<1, 64, 0, stream>>>(gstart, gend, N);
  k_grange_mark<<<(N + 255) / 256, 256, 0, stream>>>(batch, gstart, gend, N);
  k_pool<<<NGRAPH, 256, 0, stream>>>(scores, xh, xl, gstart, gend, pooled);

  // ---- classifier ----
  k_cls1<<<dim3(2, NGRAPH), 256, 0, stream>>>(pooled, cW1, cb1, hid);
  k_cls2<<<dim3(14, NGRAPH), 64, 0, stream>>>(hid, cW2, cb2, out);
}